// Round 12
// baseline (602.000 us; speedup 1.0000x reference)
//
#include <hip/hip_runtime.h>
#include <hip/hip_bf16.h>

// Problem constants
#define NPTS   512000          // B*P
#define PSEG   2000
#define INV_N  (1.0f/512000.0f)
#define EPS_BN 1e-5f

// stats layout (floats), spread-copied to kill atomic line contention:
//  S1 @    0: 32 copies x 32  (bn1: sum[16] at +c, sumsq at +16+c)
//  S2 @ 1024: 32 copies x 16  (bn2)
//  S3 @ 1536: 32 copies x 2   (bn3)
//  S4 @ 1600:  4 copies x 2048 (bn4: sum[1024] then sumsq[1024])
//  S5 @ 9792: 16 copies x 512  (bn5: sum[256] then sumsq[256])
//  zero region = 18432 floats (73728 B)
#define S1_OFF 0
#define S2_OFF 1024
#define S3_OFF 1536
#define S4_OFF 1600
#define S5_OFF 9792

using u32 = unsigned int;
using u16 = unsigned short;
using f32x4  = __attribute__((ext_vector_type(4))) float;
using bf16x8 = __attribute__((ext_vector_type(8))) short;

static __device__ __forceinline__ u16 f2bf(float f) {
    u32 u = __builtin_bit_cast(u32, f);
    u += 0x7fffu + ((u >> 16) & 1u);   // round-to-nearest-even (finite values)
    return (u16)(u >> 16);
}

static __device__ __forceinline__ void gload_lds16(const void* g, void* l) {
    __builtin_amdgcn_global_load_lds(
        (const __attribute__((address_space(1))) unsigned int*)g,
        (__attribute__((address_space(3))) unsigned int*)l, 16, 0, 0);
}

// ---------------------------------------------------------------------------
// K0: zero the stats area (73728 B). grid 18 x 256 x float4.
// ---------------------------------------------------------------------------
__global__ __launch_bounds__(256) void k_zero(float4* __restrict__ p) {
    p[blockIdx.x * 256 + threadIdx.x] = float4{0.0f, 0.0f, 0.0f, 0.0f};
}

// ---------------------------------------------------------------------------
// Recompute-not-materialize MLP chain: a1/a2/a3 never touch memory.
// Each stat kernel re-reads x (L3-resident after first pass, ~6 us) and
// recomputes the tiny MLP in registers (~7 us VALU) — cheaper than the
// 100 MB of a1/a2 round-trips it replaces.
// 500 blocks x 256 thr x 4 pts = 512000 points.
// ---------------------------------------------------------------------------

// K1: stats of a1 = x @ w1.T -> S1 (32-way spread). Nothing written but stats.
__global__ __launch_bounds__(256) void k_stat1(const float* __restrict__ x,
                                               const float* __restrict__ w1,
                                               float* __restrict__ stats) {
    __shared__ float w[512];
    __shared__ float part[4][32];
    const int t = threadIdx.x, bid = blockIdx.x;
    w[t] = w1[t]; w[t + 256] = w1[t + 256];
    __syncthreads();

    float sacc[16] = {}, qacc[16] = {};
#pragma unroll
    for (int pp = 0; pp < 4; pp++) {
        const int pt = bid * 1024 + pp * 256 + t;
        const float4* xr = (const float4*)(x + (size_t)pt * 32);
        float4 xv[8];
#pragma unroll
        for (int i = 0; i < 8; i++) xv[i] = xr[i];
#pragma unroll
        for (int c = 0; c < 16; c++) {
            const float4* wr = (const float4*)(w + c * 32);
            float s = 0.0f;
#pragma unroll
            for (int i = 0; i < 8; i++) {
                float4 wv = wr[i];
                s += xv[i].x * wv.x + xv[i].y * wv.y + xv[i].z * wv.z + xv[i].w * wv.w;
            }
            sacc[c] += s; qacc[c] += s * s;
        }
    }
    const int lane = t & 63, wave = t >> 6;
#pragma unroll
    for (int c = 0; c < 16; c++) {
        float s = sacc[c], q = qacc[c];
#pragma unroll
        for (int off = 32; off > 0; off >>= 1) {
            s += __shfl_down(s, off);
            q += __shfl_down(q, off);
        }
        if (lane == 0) { part[wave][c] = s; part[wave][16 + c] = q; }
    }
    __syncthreads();
    if (t < 32) {
        float tot = part[0][t] + part[1][t] + part[2][t] + part[3][t];
        atomicAdd(&stats[S1_OFF + (bid & 31) * 32 + t], tot);
    }
}

// K2: recompute a1 -> bn1+relu -> a2 = h1 @ w2.T; stats -> S2 (32-way spread)
__global__ __launch_bounds__(256) void k_stat2(const float* __restrict__ x,
                                               const float* __restrict__ w1,
                                               const float* __restrict__ w2,
                                               const float* __restrict__ g1,
                                               const float* __restrict__ be1,
                                               float* __restrict__ stats) {
    __shared__ float w[512];
    __shared__ float wb[128];
    __shared__ float sc1[16], sh1[16];
    __shared__ float part[4][16];
    const int t = threadIdx.x, bid = blockIdx.x;
    w[t] = w1[t]; w[t + 256] = w1[t + 256];
    if (t < 128) wb[t] = w2[t];
    if (t < 16) {
        float s = 0.0f, q = 0.0f;
#pragma unroll 8
        for (int c = 0; c < 32; c++) {
            s += stats[S1_OFF + c * 32 + t];
            q += stats[S1_OFF + c * 32 + 16 + t];
        }
        float m = s * INV_N, v = q * INV_N - m * m;
        float sl = g1[t] * rsqrtf(v + EPS_BN);
        sc1[t] = sl; sh1[t] = be1[t] - m * sl;
    }
    __syncthreads();

    float sacc[8] = {}, qacc[8] = {};
#pragma unroll
    for (int pp = 0; pp < 4; pp++) {
        const int pt = bid * 1024 + pp * 256 + t;
        const float4* xr = (const float4*)(x + (size_t)pt * 32);
        float4 xv[8];
#pragma unroll
        for (int i = 0; i < 8; i++) xv[i] = xr[i];
        float h[16];
#pragma unroll
        for (int c = 0; c < 16; c++) {
            const float4* wr = (const float4*)(w + c * 32);
            float s = 0.0f;
#pragma unroll
            for (int i = 0; i < 8; i++) {
                float4 wv = wr[i];
                s += xv[i].x * wv.x + xv[i].y * wv.y + xv[i].z * wv.z + xv[i].w * wv.w;
            }
            h[c] = fmaxf(fmaf(s, sc1[c], sh1[c]), 0.0f);
        }
#pragma unroll
        for (int c = 0; c < 8; c++) {
            float s = 0.0f;
#pragma unroll
            for (int k = 0; k < 16; k++) s += h[k] * wb[c * 16 + k];
            sacc[c] += s; qacc[c] += s * s;
        }
    }
    const int lane = t & 63, wave = t >> 6;
#pragma unroll
    for (int c = 0; c < 8; c++) {
        float s = sacc[c], q = qacc[c];
#pragma unroll
        for (int off = 32; off > 0; off >>= 1) {
            s += __shfl_down(s, off);
            q += __shfl_down(q, off);
        }
        if (lane == 0) { part[wave][c] = s; part[wave][8 + c] = q; }
    }
    __syncthreads();
    if (t < 16) {
        float tot = part[0][t] + part[1][t] + part[2][t] + part[3][t];
        atomicAdd(&stats[S2_OFF + (bid & 31) * 16 + t], tot);
    }
}

// K3: recompute a1,h1,a2 -> bn2+relu -> a3 = h2 @ w3.T; stats -> S3
__global__ __launch_bounds__(256) void k_stat3(const float* __restrict__ x,
                                               const float* __restrict__ w1,
                                               const float* __restrict__ w2,
                                               const float* __restrict__ w3,
                                               const float* __restrict__ g1,
                                               const float* __restrict__ be1,
                                               const float* __restrict__ g2,
                                               const float* __restrict__ be2,
                                               float* __restrict__ stats) {
    __shared__ float w[512];
    __shared__ float wb[128];
    __shared__ float wc[8];
    __shared__ float sc1[16], sh1[16], sc2[8], sh2[8];
    __shared__ float part[4][2];
    const int t = threadIdx.x, bid = blockIdx.x;
    w[t] = w1[t]; w[t + 256] = w1[t + 256];
    if (t < 128) wb[t] = w2[t];
    if (t < 16) {
        float s = 0.0f, q = 0.0f;
#pragma unroll 8
        for (int c = 0; c < 32; c++) {
            s += stats[S1_OFF + c * 32 + t];
            q += stats[S1_OFF + c * 32 + 16 + t];
        }
        float m = s * INV_N, v = q * INV_N - m * m;
        float sl = g1[t] * rsqrtf(v + EPS_BN);
        sc1[t] = sl; sh1[t] = be1[t] - m * sl;
    }
    if (t < 8) {
        wc[t] = w3[t];
        float s = 0.0f, q = 0.0f;
#pragma unroll 8
        for (int c = 0; c < 32; c++) {
            s += stats[S2_OFF + c * 16 + t];
            q += stats[S2_OFF + c * 16 + 8 + t];
        }
        float m = s * INV_N, v = q * INV_N - m * m;
        float sl = g2[t] * rsqrtf(v + EPS_BN);
        sc2[t] = sl; sh2[t] = be2[t] - m * sl;
    }
    __syncthreads();

    float sacc = 0.0f, qacc = 0.0f;
#pragma unroll
    for (int pp = 0; pp < 4; pp++) {
        const int pt = bid * 1024 + pp * 256 + t;
        const float4* xr = (const float4*)(x + (size_t)pt * 32);
        float4 xv[8];
#pragma unroll
        for (int i = 0; i < 8; i++) xv[i] = xr[i];
        float h[16];
#pragma unroll
        for (int c = 0; c < 16; c++) {
            const float4* wr = (const float4*)(w + c * 32);
            float s = 0.0f;
#pragma unroll
            for (int i = 0; i < 8; i++) {
                float4 wv = wr[i];
                s += xv[i].x * wv.x + xv[i].y * wv.y + xv[i].z * wv.z + xv[i].w * wv.w;
            }
            h[c] = fmaxf(fmaf(s, sc1[c], sh1[c]), 0.0f);
        }
        float a3v = 0.0f;
#pragma unroll
        for (int c = 0; c < 8; c++) {
            float s = 0.0f;
#pragma unroll
            for (int k = 0; k < 16; k++) s += h[k] * wb[c * 16 + k];
            a3v += fmaxf(fmaf(s, sc2[c], sh2[c]), 0.0f) * wc[c];
        }
        sacc += a3v; qacc += a3v * a3v;
    }
    const int lane = t & 63, wave = t >> 6;
#pragma unroll
    for (int off = 32; off > 0; off >>= 1) {
        sacc += __shfl_down(sacc, off);
        qacc += __shfl_down(qacc, off);
    }
    if (lane == 0) { part[wave][0] = sacc; part[wave][1] = qacc; }
    __syncthreads();
    if (t < 2) {
        float tot = part[0][t] + part[1][t] + part[2][t] + part[3][t];
        atomicAdd(&stats[S3_OFF + (bid & 31) * 2 + t], tot);
    }
}

// ---------------------------------------------------------------------------
// K4: recompute score per point; per-segment softmax; pooled = x*att as bf16,
//     stored PRE-SWIZZLED for the GEMM's global_load_lds A-stage.
//     One block per segment; 8 points per thread.
// ---------------------------------------------------------------------------
__global__ __launch_bounds__(256) void k_pool(const float* __restrict__ x,
                                              const float* __restrict__ w1,
                                              const float* __restrict__ w2,
                                              const float* __restrict__ w3,
                                              const float* __restrict__ g1,
                                              const float* __restrict__ be1,
                                              const float* __restrict__ g2,
                                              const float* __restrict__ be2,
                                              const float* __restrict__ g3,
                                              const float* __restrict__ be3,
                                              const float* __restrict__ stats,
                                              u16* __restrict__ pooled) {
    __shared__ float w[512];
    __shared__ float wb[128];
    __shared__ float wc[8];
    __shared__ float sc1[16], sh1[16], sc2[8], sh2[8], s3p[2];
    __shared__ float redm[4], reds[4];
    const int b = blockIdx.x, t = threadIdx.x;
    w[t] = w1[t]; w[t + 256] = w1[t + 256];
    if (t < 128) wb[t] = w2[t];
    if (t < 16) {
        float s = 0.0f, q = 0.0f;
#pragma unroll 8
        for (int c = 0; c < 32; c++) {
            s += stats[S1_OFF + c * 32 + t];
            q += stats[S1_OFF + c * 32 + 16 + t];
        }
        float m = s * INV_N, v = q * INV_N - m * m;
        float sl = g1[t] * rsqrtf(v + EPS_BN);
        sc1[t] = sl; sh1[t] = be1[t] - m * sl;
    }
    if (t < 8) {
        wc[t] = w3[t];
        float s = 0.0f, q = 0.0f;
#pragma unroll 8
        for (int c = 0; c < 32; c++) {
            s += stats[S2_OFF + c * 16 + t];
            q += stats[S2_OFF + c * 16 + 8 + t];
        }
        float m = s * INV_N, v = q * INV_N - m * m;
        float sl = g2[t] * rsqrtf(v + EPS_BN);
        sc2[t] = sl; sh2[t] = be2[t] - m * sl;
    }
    if (t == 0) {
        float sm = 0.0f, sq = 0.0f;
#pragma unroll 8
        for (int c = 0; c < 32; c++) {
            sm += stats[S3_OFF + c * 2];
            sq += stats[S3_OFF + c * 2 + 1];
        }
        float m = sm * INV_N, v = sq * INV_N - m * m;
        float sl = g3[0] * rsqrtf(v + EPS_BN);
        s3p[0] = sl; s3p[1] = be3[0] - m * sl;
    }
    __syncthreads();
    const float sc3 = s3p[0], sh3 = s3p[1];

    float sv[8];
    float mx = -1e30f;
#pragma unroll
    for (int i = 0; i < 8; i++) {
        int p = t + i * 256;
        if (p < PSEG) {
            const float4* xr = (const float4*)(x + ((size_t)b * PSEG + p) * 32);
            float4 xv[8];
#pragma unroll
            for (int u = 0; u < 8; u++) xv[u] = xr[u];
            float h[16];
#pragma unroll
            for (int c = 0; c < 16; c++) {
                const float4* wr = (const float4*)(w + c * 32);
                float s = 0.0f;
#pragma unroll
                for (int u = 0; u < 8; u++) {
                    float4 wv = wr[u];
                    s += xv[u].x * wv.x + xv[u].y * wv.y + xv[u].z * wv.z + xv[u].w * wv.w;
                }
                h[c] = fmaxf(fmaf(s, sc1[c], sh1[c]), 0.0f);
            }
            float a3v = 0.0f;
#pragma unroll
            for (int c = 0; c < 8; c++) {
                float s = 0.0f;
#pragma unroll
                for (int k = 0; k < 16; k++) s += h[k] * wb[c * 16 + k];
                a3v += fmaxf(fmaf(s, sc2[c], sh2[c]), 0.0f) * wc[c];
            }
            float val = fmaxf(fmaf(a3v, sc3, sh3), 0.0f);
            sv[i] = val; mx = fmaxf(mx, val);
        } else sv[i] = -1e30f;
    }
    const int lane = t & 63, wave = t >> 6;
#pragma unroll
    for (int off = 32; off > 0; off >>= 1) mx = fmaxf(mx, __shfl_xor(mx, off));
    if (lane == 0) redm[wave] = mx;
    __syncthreads();
    mx = fmaxf(fmaxf(redm[0], redm[1]), fmaxf(redm[2], redm[3]));

    float es = 0.0f;
#pragma unroll
    for (int i = 0; i < 8; i++) {
        int p = t + i * 256;
        if (p < PSEG) { float e = __expf(sv[i] - mx); sv[i] = e; es += e; }
    }
#pragma unroll
    for (int off = 32; off > 0; off >>= 1) es += __shfl_xor(es, off);
    if (lane == 0) reds[wave] = es;
    __syncthreads();
    const float inv = 1.0f / (reds[0] + reds[1] + reds[2] + reds[3]);

    const int swz = (b & 7) << 3;   // element-index XOR within 64-elem chunk
#pragma unroll
    for (int i = 0; i < 8; i++) {
        int p = t + i * 256;
        if (p >= PSEG) continue;
        const float att = sv[i] * inv;
        const float4* xr = (const float4*)(x + ((size_t)b * PSEG + p) * 32);
        u16* dst = pooled + (size_t)b * 64000 + (size_t)(p >> 1) * 64;
        const int half = (p & 1) << 5;
#pragma unroll
        for (int u = 0; u < 4; u++) {
            float4 f0 = xr[u * 2], f1 = xr[u * 2 + 1];
            u32 q0 = (u32)f2bf(f0.x * att) | ((u32)f2bf(f0.y * att) << 16);
            u32 q1 = (u32)f2bf(f0.z * att) | ((u32)f2bf(f0.w * att) << 16);
            u32 q2 = (u32)f2bf(f1.x * att) | ((u32)f2bf(f1.y * att) << 16);
            u32 q3 = (u32)f2bf(f1.z * att) | ((u32)f2bf(f1.w * att) << 16);
            uint4 q; q.x = q0; q.y = q1; q.z = q2; q.w = q3;
            *(uint4*)(dst + ((half | (u << 3)) ^ swz)) = q;
        }
    }
}

// ---------------------------------------------------------------------------
// K5: split-K bf16 MFMA GEMM (R9 best variant, unchanged): 3 blocks/CU +
//     counted-wait pipeline; grid (16,40), 256 thr; tile 256x64, BK=64 x 25.
// ---------------------------------------------------------------------------
__global__ __launch_bounds__(256) void k_gemm4(const u16* __restrict__ pooled,
                                               const float* __restrict__ fw1,
                                               float* __restrict__ a4p) {
    __shared__ alignas(16) char smem[49152];   // A 32KB | Bbuf0 8KB | Bbuf1 8KB

    const int t = threadIdx.x;
    const int jblk = blockIdx.x;       // 0..15 : N tile
    const int kblk = blockIdx.y;       // 0..39 : K split
    const int wave = t >> 6, lane = t & 63;
    const int kbase = kblk * 1600;

    const u16* gA = pooled + (size_t)(wave * 8 + (lane >> 3)) * 64000 + (lane & 7) * 8;
    const int jj = t >> 4;             // 0..15 : B row group
    const int ks = (t & 15) * 4;       // 0..60 : B k offset (floats)
    const float* gB = fw1 + (size_t)(jblk * 64 + jj) * 64000 + ks;

    f32x4 acc[4][4] = {};
    float4 b0, b1, b2, b3;

    // ---- prologue: A(0) -> LDS, B(0) -> regs -> Bbuf0 ----
#pragma unroll
    for (int i = 0; i < 8; i++)
        gload_lds16(gA + kbase + (size_t)i * 32 * 64000,
                    smem + wave * 1024 + i * 4096);
    {
        const float* bs = gB + kbase;
        b0 = *(const float4*)(bs);
        b1 = *(const float4*)(bs + (size_t)16 * 64000);
        b2 = *(const float4*)(bs + (size_t)32 * 64000);
        b3 = *(const float4*)(bs + (size_t)48 * 64000);
        char* Bs = smem + 32768;
#pragma unroll
        for (int i = 0; i < 4; i++) {
            const int j = i * 16 + jj;
            float4 v = (i == 0) ? b0 : (i == 1) ? b1 : (i == 2) ? b2 : b3;
            ushort4 bv;
            bv.x = f2bf(v.x); bv.y = f2bf(v.y); bv.z = f2bf(v.z); bv.w = f2bf(v.w);
            *(ushort4*)(Bs + ((j * 128 + ks * 2) ^ ((j & 7) << 4))) = bv;
        }
    }
    asm volatile("s_waitcnt vmcnt(0) lgkmcnt(0)" ::: "memory");
    __builtin_amdgcn_s_barrier();
    __builtin_amdgcn_sched_barrier(0);

    int cur = 0;
    for (int step = 0; step < 25; ++step) {
        const bool pf = (step + 1 < 25);
        // -- 1. prefetch B(t+1) into regs (flies across the MFMA cluster) --
        if (pf) {
            const float* bs = gB + kbase + (step + 1) * 64;
            b0 = *(const float4*)(bs);
            b1 = *(const float4*)(bs + (size_t)16 * 64000);
            b2 = *(const float4*)(bs + (size_t)32 * 64000);
            b3 = *(const float4*)(bs + (size_t)48 * 64000);
        }
        __builtin_amdgcn_sched_barrier(0);
        // -- 2. compute on A + Bbuf[cur] --
        const char* As = smem;
        const char* Bs = smem + 32768 + cur * 8192;
#pragma unroll
        for (int kk = 0; kk < 2; ++kk) {
            const int krow = kk * 32 + (lane >> 4) * 8;
            bf16x8 aF[4], bF[4];
#pragma unroll
            for (int mm = 0; mm < 4; mm++) {
                const int row = wave * 64 + mm * 16 + (lane & 15);
                aF[mm] = *(const bf16x8*)(As + ((row * 128 + krow * 2) ^ ((row & 7) << 4)));
            }
#pragma unroll
            for (int nn = 0; nn < 4; nn++) {
                const int col = nn * 16 + (lane & 15);
                bF[nn] = *(const bf16x8*)(Bs + ((col * 128 + krow * 2) ^ ((col & 7) << 4)));
            }
#pragma unroll
            for (int mm = 0; mm < 4; mm++)
#pragma unroll
                for (int nn = 0; nn < 4; nn++)
                    acc[mm][nn] = __builtin_amdgcn_mfma_f32_16x16x32_bf16(
                        aF[mm], bF[nn], acc[mm][nn], 0, 0, 0);
        }
        __builtin_amdgcn_sched_barrier(0);
        // -- 3. all waves done reading A(t) and Bbuf[cur] --
        __builtin_amdgcn_s_barrier();
        __builtin_amdgcn_sched_barrier(0);
        if (pf) {
            // -- 4. restage A(t+1) into the (now free) A buffer --
#pragma unroll
            for (int i = 0; i < 8; i++)
                gload_lds16(gA + kbase + (step + 1) * 64 + (size_t)i * 32 * 64000,
                            smem + wave * 1024 + i * 4096);
            __builtin_amdgcn_sched_barrier(0);
            // -- 5. write B(t+1) --
            char* Bn = smem + 32768 + (cur ^ 1) * 8192;
#pragma unroll
            for (int i = 0; i < 4; i++) {
                const int j = i * 16 + jj;
                float4 v = (i == 0) ? b0 : (i == 1) ? b1 : (i == 2) ? b2 : b3;
                ushort4 bv;
                bv.x = f2bf(v.x); bv.y = f2bf(v.y); bv.z = f2bf(v.z); bv.w = f2bf(v.w);
                *(ushort4*)(Bn + ((j * 128 + ks * 2) ^ ((j & 7) << 4))) = bv;
            }
            __builtin_amdgcn_sched_barrier(0);
            // -- 6. drain A(t+1)+B-writes, publish to all waves --
            asm volatile("s_waitcnt vmcnt(0) lgkmcnt(0)" ::: "memory");
            __builtin_amdgcn_s_barrier();
            __builtin_amdgcn_sched_barrier(0);
        }
        cur ^= 1;
    }

    // epilogue: coalesced stores to per-kblk partial buffer
    float* dst = a4p + (size_t)kblk * 262144;
#pragma unroll
    for (int mm = 0; mm < 4; mm++)
#pragma unroll
        for (int nn = 0; nn < 4; nn++)
#pragma unroll
            for (int r = 0; r < 4; r++) {
                const int row = wave * 64 + mm * 16 + (lane >> 4) * 4 + r;
                const int col = jblk * 64 + nn * 16 + (lane & 15);
                dst[(size_t)row * 1024 + col] = acc[mm][nn][r];
            }
}

// ---------------------------------------------------------------------------
// K6: reduce 40 split-K partials -> a4 [256,1024]; BN4 stats -> S4 (4-spread)
// ---------------------------------------------------------------------------
__global__ __launch_bounds__(256) void k_red4(const float* __restrict__ a4p,
                                              float* __restrict__ a4,
                                              float* __restrict__ stats) {
    const int i = blockIdx.x, t = threadIdx.x;
    float4 s = {0.0f, 0.0f, 0.0f, 0.0f};
#pragma unroll 8
    for (int kb = 0; kb < 40; kb++) {
        float4 v = *(const float4*)(a4p + (size_t)kb * 262144 + (size_t)i * 1024 + t * 4);
        s.x += v.x; s.y += v.y; s.z += v.z; s.w += v.w;
    }
    *(float4*)(a4 + (size_t)i * 1024 + t * 4) = s;
    const int j = t * 4;
    float* s4 = stats + S4_OFF + (i & 3) * 2048;
    atomicAdd(&s4[j + 0], s.x);
    atomicAdd(&s4[j + 1], s.y);
    atomicAdd(&s4[j + 2], s.z);
    atomicAdd(&s4[j + 3], s.w);
    atomicAdd(&s4[1024 + j + 0], s.x * s.x);
    atomicAdd(&s4[1024 + j + 1], s.y * s.y);
    atomicAdd(&s4[1024 + j + 2], s.z * s.z);
    atomicAdd(&s4[1024 + j + 3], s.w * s.w);
}

// ---------------------------------------------------------------------------
// K7: h4 = relu(bn4(a4)); a5 = h4 @ fw2.T; BN5 stats -> S5 (16-spread)
// ---------------------------------------------------------------------------
__global__ __launch_bounds__(256) void k_fc2(const float* __restrict__ a4,
                                             const float* __restrict__ fg1,
                                             const float* __restrict__ fbe1,
                                             const float* __restrict__ fw2,
                                             float* __restrict__ stats,
                                             float* __restrict__ a5) {
    __shared__ alignas(16) float h[1024];
    const int i = blockIdx.x, t = threadIdx.x;
#pragma unroll
    for (int u = 0; u < 4; u++) {
        const int k = u * 256 + t;
        float s = 0.0f, q = 0.0f;
#pragma unroll
        for (int c = 0; c < 4; c++) {
            s += stats[S4_OFF + c * 2048 + k];
            q += stats[S4_OFF + c * 2048 + 1024 + k];
        }
        float m  = s * (1.0f / 256.0f);
        float v  = q * (1.0f / 256.0f) - m * m;
        float sc = fg1[k] * rsqrtf(v + EPS_BN);
        float sh = fbe1[k] - m * sc;
        h[k] = fmaxf(fmaf(a4[(size_t)i * 1024 + k], sc, sh), 0.0f);
    }
    __syncthreads();
    const float4* wr = (const float4*)(fw2 + (size_t)t * 1024);
    const float4* hr = (const float4*)h;
    float s = 0.0f;
#pragma unroll 4
    for (int u = 0; u < 256; u++) {
        float4 w = wr[u], hv = hr[u];
        s += w.x * hv.x + w.y * hv.y + w.z * hv.z + w.w * hv.w;
    }
    a5[(size_t)i * 256 + t] = s;
    float* s5 = stats + S5_OFF + (i & 15) * 512;
    atomicAdd(&s5[t], s);
    atomicAdd(&s5[256 + t], s * s);
}

// ---------------------------------------------------------------------------
// K8: r = relu(bn5(a5)); out = r / max(||r||_2, 1e-12) per row
// ---------------------------------------------------------------------------
__global__ __launch_bounds__(256) void k_norm(const float* __restrict__ a5,
                                              const float* __restrict__ fg2,
                                              const float* __restrict__ fbe2,
                                              const float* __restrict__ stats,
                                              float* __restrict__ out) {
    const int i = blockIdx.x, t = threadIdx.x;
    float s = 0.0f, q2 = 0.0f;
#pragma unroll
    for (int c = 0; c < 16; c++) {
        s  += stats[S5_OFF + c * 512 + t];
        q2 += stats[S5_OFF + c * 512 + 256 + t];
    }
    float m  = s * (1.0f / 256.0f);
    float v  = q2 * (1.0f / 256.0f) - m * m;
    float sc = fg2[t] * rsqrtf(v + EPS_BN);
    float sh = fbe2[t] - m * sc;
    float r = fmaxf(fmaf(a5[(size_t)i * 256 + t], sc, sh), 0.0f);

    float q = r * r;
    const int lane = t & 63, wave = t >> 6;
#pragma unroll
    for (int off = 32; off > 0; off >>= 1) q += __shfl_xor(q, off);
    __shared__ float red[4];
    if (lane == 0) red[wave] = q;
    __syncthreads();
    float tot = red[0] + red[1] + red[2] + red[3];
    float nrm = fmaxf(sqrtf(tot), 1e-12f);
    out[(size_t)i * 256 + t] = r / nrm;
}

// ---------------------------------------------------------------------------
extern "C" void kernel_launch(void* const* d_in, const int* in_sizes, int n_in,
                              void* d_out, int out_size, void* d_ws, size_t ws_size,
                              hipStream_t stream) {
    const float* x   = (const float*)d_in[0];
    // d_in[1] = length (all 2000) — unused (dense reshape)
    const float* w1  = (const float*)d_in[2];
    const float* g1  = (const float*)d_in[4];
    const float* be1 = (const float*)d_in[5];
    const float* w2  = (const float*)d_in[6];
    const float* g2  = (const float*)d_in[8];
    const float* be2 = (const float*)d_in[9];
    const float* w3  = (const float*)d_in[10];
    const float* g3  = (const float*)d_in[12];
    const float* be3 = (const float*)d_in[13];
    const float* fw1 = (const float*)d_in[14];
    const float* fg1 = (const float*)d_in[16];
    const float* fbe1= (const float*)d_in[17];
    const float* fw2 = (const float*)d_in[18];
    const float* fg2 = (const float*)d_in[20];
    const float* fbe2= (const float*)d_in[21];
    // biases b1,b2,b3,fb1,fb2 cancel exactly under BatchNorm mean subtraction.
    float* out = (float*)d_out;

    // ws layout: [stats 72KB | a4 1MB | a5 256KB | a4p 40MB | pooled 32.77MB]
    // (a1/a2/a3 eliminated — MLP chain recomputes from L3-resident x)
    char* ws = (char*)d_ws;
    float* stats = (float*)ws;                              // 73728 B (zeroed)
    float* a4 = (float*)(ws + 73728);                       // [256,1024] 1 MB
    float* a5 = (float*)(ws + 73728 + 1048576);             // [256,256] 256 KB
    float* a4p = (float*)(ws + 73728 + 1048576 + 262144);   // [40,256,1024] 40 MB
    u16*   pooled = (u16*)(ws + 73728 + 1048576 + 262144 + 41943040);

    k_zero<<<18, 256, 0, stream>>>((float4*)ws);            // stats area
    k_stat1<<<500, 256, 0, stream>>>(x, w1, stats);
    k_stat2<<<500, 256, 0, stream>>>(x, w1, w2, g1, be1, stats);
    k_stat3<<<500, 256, 0, stream>>>(x, w1, w2, w3, g1, be1, g2, be2, stats);
    k_pool<<<256, 256, 0, stream>>>(x, w1, w2, w3, g1, be1, g2, be2, g3, be3,
                                    stats, pooled);
    k_gemm4<<<dim3(16, 40), 256, 0, stream>>>(pooled, fw1, a4p);
    k_red4<<<256, 256, 0, stream>>>(a4p, a4, stats);
    k_fc2<<<256, 256, 0, stream>>>(a4, fg1, fbe1, fw2, stats, a5);
    k_norm<<<256, 256, 0, stream>>>(a5, fg2, fbe2, stats, out);
}

// Round 13
// 266.954 us; speedup vs baseline: 2.2551x; 2.2551x over previous
//
#include <hip/hip_runtime.h>
#include <hip/hip_bf16.h>

// Problem constants
#define NPTS   512000          // B*P
#define PSEG   2000
#define INV_N  (1.0f/512000.0f)
#define EPS_BN 1e-5f

// stats layout (floats), spread-copied to kill atomic line contention:
//  S1 @    0: 32 copies x 32  (bn1: sum[16] at +c, sumsq at +16+c)
//  S2 @ 1024: 32 copies x 16  (bn2)
//  S3 @ 1536: 32 copies x 2   (bn3)
//  S4 @ 1600:  4 copies x 2048 (bn4: sum[1024] then sumsq[1024])
//  S5 @ 9792: 16 copies x 512  (bn5: sum[256] then sumsq[256])
//  zero region = 18432 floats (73728 B)
#define S1_OFF 0
#define S2_OFF 1024
#define S3_OFF 1536
#define S4_OFF 1600
#define S5_OFF 9792

using u32 = unsigned int;
using u16 = unsigned short;
using f32x4  = __attribute__((ext_vector_type(4))) float;
using bf16x8 = __attribute__((ext_vector_type(8))) short;

static __device__ __forceinline__ u16 f2bf(float f) {
    u32 u = __builtin_bit_cast(u32, f);
    u += 0x7fffu + ((u >> 16) & 1u);   // round-to-nearest-even (finite values)
    return (u16)(u >> 16);
}

static __device__ __forceinline__ void gload_lds16(const void* g, void* l) {
    __builtin_amdgcn_global_load_lds(
        (const __attribute__((address_space(1))) unsigned int*)g,
        (__attribute__((address_space(3))) unsigned int*)l, 16, 0, 0);
}

// ---------------------------------------------------------------------------
// K0: zero the stats area (73728 B). grid 18 x 256 x float4.
// ---------------------------------------------------------------------------
__global__ __launch_bounds__(256) void k_zero(float4* __restrict__ p) {
    p[blockIdx.x * 256 + threadIdx.x] = float4{0.0f, 0.0f, 0.0f, 0.0f};
}

// ---------------------------------------------------------------------------
// K1: a1 = x @ w1.T  [N,16]; per-channel sum/sumsq -> S1 (32-way spread)
// ---------------------------------------------------------------------------
__global__ __launch_bounds__(256) void k_mlp1(const float* __restrict__ x,
                                              const float* __restrict__ w1,
                                              float* __restrict__ a1,
                                              float* __restrict__ stats) {
    __shared__ float w[512];
    __shared__ float part[4][32];
    const int t = threadIdx.x;
    w[t] = w1[t]; w[t + 256] = w1[t + 256];
    __syncthreads();

    const int idx = blockIdx.x * 256 + t;
    const float4* xr = (const float4*)(x + (size_t)idx * 32);
    float4 xv[8];
#pragma unroll
    for (int i = 0; i < 8; i++) xv[i] = xr[i];

    float h[16];
#pragma unroll
    for (int c = 0; c < 16; c++) {
        float s = 0.0f;
        const float4* wr = (const float4*)(w + c * 32);
#pragma unroll
        for (int i = 0; i < 8; i++) {
            float4 wv = wr[i];
            s += xv[i].x * wv.x + xv[i].y * wv.y + xv[i].z * wv.z + xv[i].w * wv.w;
        }
        h[c] = s;
    }

    float4* ar = (float4*)(a1 + (size_t)idx * 16);
#pragma unroll
    for (int i = 0; i < 4; i++) {
        float4 o; o.x = h[i*4+0]; o.y = h[i*4+1]; o.z = h[i*4+2]; o.w = h[i*4+3];
        ar[i] = o;
    }

    const int lane = t & 63, wave = t >> 6;
#pragma unroll
    for (int c = 0; c < 16; c++) {
        float s = h[c], q = h[c] * h[c];
#pragma unroll
        for (int off = 32; off > 0; off >>= 1) {
            s += __shfl_down(s, off);
            q += __shfl_down(q, off);
        }
        if (lane == 0) { part[wave][c] = s; part[wave][16 + c] = q; }
    }
    __syncthreads();
    if (t < 32) {
        float tot = part[0][t] + part[1][t] + part[2][t] + part[3][t];
        atomicAdd(&stats[S1_OFF + (blockIdx.x & 31) * 32 + t], tot);
    }
}

// ---------------------------------------------------------------------------
// K2: h1 = relu(bn1(a1)); a2 = h1 @ w2.T [N,8]; stats -> S2 (32-way spread)
// ---------------------------------------------------------------------------
__global__ __launch_bounds__(256) void k_mlp2(const float* __restrict__ a1,
                                              const float* __restrict__ w2,
                                              const float* __restrict__ g1,
                                              const float* __restrict__ be1,
                                              float* __restrict__ a2,
                                              float* __restrict__ stats) {
    __shared__ float w[128];
    __shared__ float sc[16], sh[16];
    __shared__ float part[4][16];
    const int t = threadIdx.x;
    if (t < 128) w[t] = w2[t];
    if (t < 16) {
        float s = 0.0f, q = 0.0f;
#pragma unroll 8
        for (int c = 0; c < 32; c++) {
            s += stats[S1_OFF + c * 32 + t];
            q += stats[S1_OFF + c * 32 + 16 + t];
        }
        float m = s * INV_N;
        float v = q * INV_N - m * m;
        float sl = g1[t] * rsqrtf(v + EPS_BN);
        sc[t] = sl; sh[t] = be1[t] - m * sl;
    }
    __syncthreads();

    const int idx = blockIdx.x * 256 + t;
    const float4* ar = (const float4*)(a1 + (size_t)idx * 16);
    float h[16];
#pragma unroll
    for (int i = 0; i < 4; i++) {
        float4 v4 = ar[i];
        h[i*4+0] = v4.x; h[i*4+1] = v4.y; h[i*4+2] = v4.z; h[i*4+3] = v4.w;
    }
#pragma unroll
    for (int c = 0; c < 16; c++) h[c] = fmaxf(fmaf(h[c], sc[c], sh[c]), 0.0f);

    float o[8];
#pragma unroll
    for (int c = 0; c < 8; c++) {
        float s = 0.0f;
#pragma unroll
        for (int k = 0; k < 16; k++) s += h[k] * w[c * 16 + k];
        o[c] = s;
    }
    float4* orp = (float4*)(a2 + (size_t)idx * 8);
    float4 o0; o0.x=o[0]; o0.y=o[1]; o0.z=o[2]; o0.w=o[3];
    float4 o1; o1.x=o[4]; o1.y=o[5]; o1.z=o[6]; o1.w=o[7];
    orp[0] = o0; orp[1] = o1;

    const int lane = t & 63, wave = t >> 6;
#pragma unroll
    for (int c = 0; c < 8; c++) {
        float s = o[c], q = o[c] * o[c];
#pragma unroll
        for (int off = 32; off > 0; off >>= 1) {
            s += __shfl_down(s, off);
            q += __shfl_down(q, off);
        }
        if (lane == 0) { part[wave][c] = s; part[wave][8 + c] = q; }
    }
    __syncthreads();
    if (t < 16) {
        float tot = part[0][t] + part[1][t] + part[2][t] + part[3][t];
        atomicAdd(&stats[S2_OFF + (blockIdx.x & 31) * 16 + t], tot);
    }
}

// ---------------------------------------------------------------------------
// K3: h2 = relu(bn2(a2)); a3 = h2 @ w3.T [N]; stats -> S3 (32-way spread)
// ---------------------------------------------------------------------------
__global__ __launch_bounds__(256) void k_mlp3(const float* __restrict__ a2,
                                              const float* __restrict__ w3,
                                              const float* __restrict__ g2,
                                              const float* __restrict__ be2,
                                              float* __restrict__ a3,
                                              float* __restrict__ stats) {
    __shared__ float w[8], sc[8], sh[8];
    __shared__ float part[4][2];
    const int t = threadIdx.x;
    if (t < 8) {
        w[t] = w3[t];
        float s = 0.0f, q = 0.0f;
#pragma unroll 8
        for (int c = 0; c < 32; c++) {
            s += stats[S2_OFF + c * 16 + t];
            q += stats[S2_OFF + c * 16 + 8 + t];
        }
        float m = s * INV_N;
        float v = q * INV_N - m * m;
        float sl = g2[t] * rsqrtf(v + EPS_BN);
        sc[t] = sl; sh[t] = be2[t] - m * sl;
    }
    __syncthreads();

    const int idx = blockIdx.x * 256 + t;
    const float4* ar = (const float4*)(a2 + (size_t)idx * 8);
    float4 v0 = ar[0], v1 = ar[1];
    float h[8] = {v0.x, v0.y, v0.z, v0.w, v1.x, v1.y, v1.z, v1.w};
    float s = 0.0f;
#pragma unroll
    for (int c = 0; c < 8; c++) s += fmaxf(fmaf(h[c], sc[c], sh[c]), 0.0f) * w[c];
    a3[idx] = s;

    const int lane = t & 63, wave = t >> 6;
    float q = s * s;
    float ss = s;
#pragma unroll
    for (int off = 32; off > 0; off >>= 1) {
        ss += __shfl_down(ss, off);
        q  += __shfl_down(q, off);
    }
    if (lane == 0) { part[wave][0] = ss; part[wave][1] = q; }
    __syncthreads();
    if (t < 2) {
        float tot = part[0][t] + part[1][t] + part[2][t] + part[3][t];
        atomicAdd(&stats[S3_OFF + (blockIdx.x & 31) * 2 + t], tot);
    }
}

// ---------------------------------------------------------------------------
// K4: score = relu(bn3(a3)); per-segment softmax; pooled = x*att as bf16,
//     stored PRE-SWIZZLED for the GEMM's global_load_lds A-stage.
// ---------------------------------------------------------------------------
__global__ __launch_bounds__(256) void k_pool(const float* __restrict__ a3,
                                              const float* __restrict__ x,
                                              const float* __restrict__ g3,
                                              const float* __restrict__ be3,
                                              const float* __restrict__ stats,
                                              u16* __restrict__ pooled) {
    const int b = blockIdx.x, t = threadIdx.x;
    float sm = 0.0f, sq = 0.0f;
#pragma unroll 8
    for (int c = 0; c < 32; c++) {
        sm += stats[S3_OFF + c * 2];
        sq += stats[S3_OFF + c * 2 + 1];
    }
    const float m  = sm * INV_N;
    const float v  = sq * INV_N - m * m;
    const float sc = g3[0] * rsqrtf(v + EPS_BN);
    const float sh = be3[0] - m * sc;

    float sv[8];
    float mx = -1e30f;
#pragma unroll
    for (int i = 0; i < 8; i++) {
        int p = t + i * 256;
        if (p < PSEG) {
            float val = fmaxf(fmaf(a3[(size_t)b * PSEG + p], sc, sh), 0.0f);
            sv[i] = val; mx = fmaxf(mx, val);
        } else sv[i] = -1e30f;
    }
    const int lane = t & 63, wave = t >> 6;
    __shared__ float redm[4], reds[4];
#pragma unroll
    for (int off = 32; off > 0; off >>= 1) mx = fmaxf(mx, __shfl_xor(mx, off));
    if (lane == 0) redm[wave] = mx;
    __syncthreads();
    mx = fmaxf(fmaxf(redm[0], redm[1]), fmaxf(redm[2], redm[3]));

    float es = 0.0f;
#pragma unroll
    for (int i = 0; i < 8; i++) {
        int p = t + i * 256;
        if (p < PSEG) { float e = __expf(sv[i] - mx); sv[i] = e; es += e; }
    }
#pragma unroll
    for (int off = 32; off > 0; off >>= 1) es += __shfl_xor(es, off);
    if (lane == 0) reds[wave] = es;
    __syncthreads();
    const float inv = 1.0f / (reds[0] + reds[1] + reds[2] + reds[3]);

    const int swz = (b & 7) << 3;   // element-index XOR within 64-elem chunk
#pragma unroll
    for (int i = 0; i < 8; i++) {
        int p = t + i * 256;
        if (p >= PSEG) continue;
        const float att = sv[i] * inv;
        const float4* xr = (const float4*)(x + ((size_t)b * PSEG + p) * 32);
        u16* dst = pooled + (size_t)b * 64000 + (size_t)(p >> 1) * 64;
        const int half = (p & 1) << 5;
#pragma unroll
        for (int u = 0; u < 4; u++) {
            float4 f0 = xr[u * 2], f1 = xr[u * 2 + 1];
            u32 q0 = (u32)f2bf(f0.x * att) | ((u32)f2bf(f0.y * att) << 16);
            u32 q1 = (u32)f2bf(f0.z * att) | ((u32)f2bf(f0.w * att) << 16);
            u32 q2 = (u32)f2bf(f1.x * att) | ((u32)f2bf(f1.y * att) << 16);
            u32 q3 = (u32)f2bf(f1.z * att) | ((u32)f2bf(f1.w * att) << 16);
            uint4 q; q.x = q0; q.y = q1; q.z = q2; q.w = q3;
            *(uint4*)(dst + ((half | (u << 3)) ^ swz)) = q;
        }
    }
}

// ---------------------------------------------------------------------------
// K5: split-K bf16 MFMA GEMM v6 — 2-deep counted-vmcnt pipeline (T3/T4).
//   Per step, 12 loads of step t+2 stay IN FLIGHT ACROSS the barriers; the
//   per-step vmcnt(0) drain (R8/R9's stall) is gone. LDS: A dbuf 2x32KB +
//   B dbuf 2x8KB = 80KB -> exactly 2 blocks/CU. grid (16,40), 256 thr.
//   vmcnt arithmetic (issue order pinned by sched_barrier):
//     steady outstanding at post-compute: B(t+1)=4 oldest, A(t+1)=8
//     vmcnt(8)  -> B(t+1) regs ready -> cvt+ds_write
//     issue B(t+2)[4] + A(t+2)[8]    -> outstanding 20
//     vmcnt(12) -> A(t+1) in LDS; 12 loads fly across the barrier.
// ---------------------------------------------------------------------------
__global__ __launch_bounds__(256) void k_gemm4(const u16* __restrict__ pooled,
                                               const float* __restrict__ fw1,
                                               float* __restrict__ a4p) {
    __shared__ alignas(16) char smem[81920];   // A0 32K | A1 32K | B0 8K | B1 8K

    const int t = threadIdx.x;
    const int jblk = blockIdx.x;       // 0..15 : N tile
    const int kblk = blockIdx.y;       // 0..39 : K split
    const int wave = t >> 6, lane = t & 63;
    const int kbase = kblk * 1600;

    const u16* gA = pooled + (size_t)(wave * 8 + (lane >> 3)) * 64000 + (lane & 7) * 8 + kbase;
    const int jj = t >> 4;             // 0..15 : B row group
    const int ks = (t & 15) * 4;       // 0..60 : B k offset (floats)
    const float* gB = fw1 + (size_t)(jblk * 64 + jj) * 64000 + ks + kbase;

    f32x4 acc[4][4] = {};
    float4 b0, b1, b2, b3;

#define ISSUE_B(STEP) {                                                       \
        const float* bs = gB + (STEP) * 64;                                   \
        b0 = *(const float4*)(bs);                                            \
        b1 = *(const float4*)(bs + (size_t)16 * 64000);                       \
        b2 = *(const float4*)(bs + (size_t)32 * 64000);                       \
        b3 = *(const float4*)(bs + (size_t)48 * 64000); }
#define ISSUE_A(STEP, BUF) {                                                  \
        _Pragma("unroll")                                                     \
        for (int i = 0; i < 8; i++)                                           \
            gload_lds16(gA + (STEP) * 64 + (size_t)i * 32 * 64000,            \
                        smem + (BUF) * 32768 + wave * 1024 + i * 4096); }
#define WRITE_B(BUF) {                                                        \
        char* Bw = smem + 65536 + (BUF) * 8192;                               \
        _Pragma("unroll")                                                     \
        for (int i = 0; i < 4; i++) {                                         \
            const int j = i * 16 + jj;                                        \
            float4 v = (i == 0) ? b0 : (i == 1) ? b1 : (i == 2) ? b2 : b3;    \
            ushort4 bv;                                                       \
            bv.x = f2bf(v.x); bv.y = f2bf(v.y);                               \
            bv.z = f2bf(v.z); bv.w = f2bf(v.w);                               \
            *(ushort4*)(Bw + ((j * 128 + ks * 2) ^ ((j & 7) << 4))) = bv; } }

    // ---- prologue: stage steps 0 and 1 ----
    ISSUE_B(0);
    __builtin_amdgcn_sched_barrier(0);
    ISSUE_A(0, 0);
    __builtin_amdgcn_sched_barrier(0);
    asm volatile("s_waitcnt vmcnt(8)" ::: "memory");     // B(0) regs ready
    __builtin_amdgcn_sched_barrier(0);
    WRITE_B(0);
    ISSUE_B(1);
    __builtin_amdgcn_sched_barrier(0);
    ISSUE_A(1, 1);
    __builtin_amdgcn_sched_barrier(0);
    asm volatile("s_waitcnt vmcnt(12) lgkmcnt(0)" ::: "memory");  // A(0) in LDS
    __builtin_amdgcn_sched_barrier(0);
    __builtin_amdgcn_s_barrier();

    int cur = 0;
#pragma unroll 1
    for (int step = 0; step < 25; ++step) {
        // -- compute on A[cur], B[cur] --
        const char* As = smem + cur * 32768;
        const char* Bs = smem + 65536 + cur * 8192;
        __builtin_amdgcn_s_setprio(1);
#pragma unroll
        for (int kk = 0; kk < 2; ++kk) {
            const int krow = kk * 32 + (lane >> 4) * 8;
            bf16x8 aF[4], bF[4];
#pragma unroll
            for (int mm = 0; mm < 4; mm++) {
                const int row = wave * 64 + mm * 16 + (lane & 15);
                aF[mm] = *(const bf16x8*)(As + ((row * 128 + krow * 2) ^ ((row & 7) << 4)));
            }
#pragma unroll
            for (int nn = 0; nn < 4; nn++) {
                const int col = nn * 16 + (lane & 15);
                bF[nn] = *(const bf16x8*)(Bs + ((col * 128 + krow * 2) ^ ((col & 7) << 4)));
            }
#pragma unroll
            for (int mm = 0; mm < 4; mm++)
#pragma unroll
                for (int nn = 0; nn < 4; nn++)
                    acc[mm][nn] = __builtin_amdgcn_mfma_f32_16x16x32_bf16(
                        aF[mm], bF[nn], acc[mm][nn], 0, 0, 0);
        }
        __builtin_amdgcn_s_setprio(0);
        __builtin_amdgcn_sched_barrier(0);
        __builtin_amdgcn_s_barrier();                 // all waves done with [cur]
        __builtin_amdgcn_sched_barrier(0);
        if (step + 1 < 25) {
            asm volatile("s_waitcnt vmcnt(8)" ::: "memory");   // B(t+1) regs ready
            __builtin_amdgcn_sched_barrier(0);
            WRITE_B(cur ^ 1);
            __builtin_amdgcn_sched_barrier(0);
            if (step + 2 < 25) {
                ISSUE_B(step + 2);
                __builtin_amdgcn_sched_barrier(0);
                ISSUE_A(step + 2, cur);               // buffer just released above
                __builtin_amdgcn_sched_barrier(0);
                asm volatile("s_waitcnt vmcnt(12) lgkmcnt(0)" ::: "memory"); // A(t+1) in LDS
            } else {
                asm volatile("s_waitcnt vmcnt(0) lgkmcnt(0)" ::: "memory");  // tail drain
            }
            __builtin_amdgcn_sched_barrier(0);
            __builtin_amdgcn_s_barrier();
            __builtin_amdgcn_sched_barrier(0);
        }
        cur ^= 1;
    }
#undef ISSUE_B
#undef ISSUE_A
#undef WRITE_B

    // epilogue: coalesced stores to per-kblk partial buffer
    float* dst = a4p + (size_t)kblk * 262144;
#pragma unroll
    for (int mm = 0; mm < 4; mm++)
#pragma unroll
        for (int nn = 0; nn < 4; nn++)
#pragma unroll
            for (int r = 0; r < 4; r++) {
                const int row = wave * 64 + mm * 16 + (lane >> 4) * 4 + r;
                const int col = jblk * 64 + nn * 16 + (lane & 15);
                dst[(size_t)row * 1024 + col] = acc[mm][nn][r];
            }
}

// ---------------------------------------------------------------------------
// K6: reduce 40 split-K partials -> a4 [256,1024]; BN4 stats -> S4 (4-spread)
// ---------------------------------------------------------------------------
__global__ __launch_bounds__(256) void k_red4(const float* __restrict__ a4p,
                                              float* __restrict__ a4,
                                              float* __restrict__ stats) {
    const int i = blockIdx.x, t = threadIdx.x;
    float4 s = {0.0f, 0.0f, 0.0f, 0.0f};
#pragma unroll 8
    for (int kb = 0; kb < 40; kb++) {
        float4 v = *(const float4*)(a4p + (size_t)kb * 262144 + (size_t)i * 1024 + t * 4);
        s.x += v.x; s.y += v.y; s.z += v.z; s.w += v.w;
    }
    *(float4*)(a4 + (size_t)i * 1024 + t * 4) = s;
    const int j = t * 4;
    float* s4 = stats + S4_OFF + (i & 3) * 2048;
    atomicAdd(&s4[j + 0], s.x);
    atomicAdd(&s4[j + 1], s.y);
    atomicAdd(&s4[j + 2], s.z);
    atomicAdd(&s4[j + 3], s.w);
    atomicAdd(&s4[1024 + j + 0], s.x * s.x);
    atomicAdd(&s4[1024 + j + 1], s.y * s.y);
    atomicAdd(&s4[1024 + j + 2], s.z * s.z);
    atomicAdd(&s4[1024 + j + 3], s.w * s.w);
}

// ---------------------------------------------------------------------------
// K7: h4 = relu(bn4(a4)); a5 = h4 @ fw2.T; BN5 stats -> S5 (16-spread)
// ---------------------------------------------------------------------------
__global__ __launch_bounds__(256) void k_fc2(const float* __restrict__ a4,
                                             const float* __restrict__ fg1,
                                             const float* __restrict__ fbe1,
                                             const float* __restrict__ fw2,
                                             float* __restrict__ stats,
                                             float* __restrict__ a5) {
    __shared__ alignas(16) float h[1024];
    const int i = blockIdx.x, t = threadIdx.x;
#pragma unroll
    for (int u = 0; u < 4; u++) {
        const int k = u * 256 + t;
        float s = 0.0f, q = 0.0f;
#pragma unroll
        for (int c = 0; c < 4; c++) {
            s += stats[S4_OFF + c * 2048 + k];
            q += stats[S4_OFF + c * 2048 + 1024 + k];
        }
        float m  = s * (1.0f / 256.0f);
        float v  = q * (1.0f / 256.0f) - m * m;
        float sc = fg1[k] * rsqrtf(v + EPS_BN);
        float sh = fbe1[k] - m * sc;
        h[k] = fmaxf(fmaf(a4[(size_t)i * 1024 + k], sc, sh), 0.0f);
    }
    __syncthreads();
    const float4* wr = (const float4*)(fw2 + (size_t)t * 1024);
    const float4* hr = (const float4*)h;
    float s = 0.0f;
#pragma unroll 4
    for (int u = 0; u < 256; u++) {
        float4 w = wr[u], hv = hr[u];
        s += w.x * hv.x + w.y * hv.y + w.z * hv.z + w.w * hv.w;
    }
    a5[(size_t)i * 256 + t] = s;
    float* s5 = stats + S5_OFF + (i & 15) * 512;
    atomicAdd(&s5[t], s);
    atomicAdd(&s5[256 + t], s * s);
}

// ---------------------------------------------------------------------------
// K8: r = relu(bn5(a5)); out = r / max(||r||_2, 1e-12) per row
// ---------------------------------------------------------------------------
__global__ __launch_bounds__(256) void k_norm(const float* __restrict__ a5,
                                              const float* __restrict__ fg2,
                                              const float* __restrict__ fbe2,
                                              const float* __restrict__ stats,
                                              float* __restrict__ out) {
    const int i = blockIdx.x, t = threadIdx.x;
    float s = 0.0f, q2 = 0.0f;
#pragma unroll
    for (int c = 0; c < 16; c++) {
        s  += stats[S5_OFF + c * 512 + t];
        q2 += stats[S5_OFF + c * 512 + 256 + t];
    }
    float m  = s * (1.0f / 256.0f);
    float v  = q2 * (1.0f / 256.0f) - m * m;
    float sc = fg2[t] * rsqrtf(v + EPS_BN);
    float sh = fbe2[t] - m * sc;
    float r = fmaxf(fmaf(a5[(size_t)i * 256 + t], sc, sh), 0.0f);

    float q = r * r;
    const int lane = t & 63, wave = t >> 6;
#pragma unroll
    for (int off = 32; off > 0; off >>= 1) q += __shfl_xor(q, off);
    __shared__ float red[4];
    if (lane == 0) red[wave] = q;
    __syncthreads();
    float tot = red[0] + red[1] + red[2] + red[3];
    float nrm = fmaxf(sqrtf(tot), 1e-12f);
    out[(size_t)i * 256 + t] = r / nrm;
}

// ---------------------------------------------------------------------------
extern "C" void kernel_launch(void* const* d_in, const int* in_sizes, int n_in,
                              void* d_out, int out_size, void* d_ws, size_t ws_size,
                              hipStream_t stream) {
    const float* x   = (const float*)d_in[0];
    // d_in[1] = length (all 2000) — unused (dense reshape)
    const float* w1  = (const float*)d_in[2];
    const float* g1  = (const float*)d_in[4];
    const float* be1 = (const float*)d_in[5];
    const float* w2  = (const float*)d_in[6];
    const float* g2  = (const float*)d_in[8];
    const float* be2 = (const float*)d_in[9];
    const float* w3  = (const float*)d_in[10];
    const float* g3  = (const float*)d_in[12];
    const float* be3 = (const float*)d_in[13];
    const float* fw1 = (const float*)d_in[14];
    const float* fg1 = (const float*)d_in[16];
    const float* fbe1= (const float*)d_in[17];
    const float* fw2 = (const float*)d_in[18];
    const float* fg2 = (const float*)d_in[20];
    const float* fbe2= (const float*)d_in[21];
    // biases b1,b2,b3,fb1,fb2 cancel exactly under BatchNorm mean subtraction.
    float* out = (float*)d_out;

    // ws layout: [stats 72KB | a4 1MB | a5 256KB | a4p 40MB | a1/pooled | a2 | a3]
    char* ws = (char*)d_ws;
    float* stats = (float*)ws;                              // 73728 B (zeroed)
    float* a4 = (float*)(ws + 73728);                       // [256,1024] 1 MB
    float* a5 = (float*)(ws + 73728 + 1048576);             // [256,256] 256 KB
    float* a4p = (float*)(ws + 73728 + 1048576 + 262144);   // [40,256,1024] 40 MB
    char*  big = ws + 73728 + 1048576 + 262144 + 41943040;
    float* a1 = (float*)big;                                // [N,16] f32 = 32,768,000 B
    u16*   pooled = (u16*)big;                              // aliases a1 (a1 dead by then)
    float* a2 = (float*)(big + 32768000);                   // [N,8]  f32 = 16,384,000 B
    float* a3 = (float*)(big + 32768000 + 16384000);        // [N]    f32 =  2,048,000 B

    k_zero<<<18, 256, 0, stream>>>((float4*)ws);            // stats area
    k_mlp1<<<2000, 256, 0, stream>>>(x, w1, a1, stats);
    k_mlp2<<<2000, 256, 0, stream>>>(a1, w2, g1, be1, a2, stats);
    k_mlp3<<<2000, 256, 0, stream>>>(a2, w3, g2, be2, a3, stats);
    k_pool<<<256, 256, 0, stream>>>(a3, x, g3, be3, stats, pooled);
    k_gemm4<<<dim3(16, 40), 256, 0, stream>>>(pooled, fw1, a4p);
    k_red4<<<256, 256, 0, stream>>>(a4p, a4, stats);
    k_fc2<<<256, 256, 0, stream>>>(a4, fg1, fbe1, fw2, stats, a5);
    k_norm<<<256, 256, 0, stream>>>(a5, fg2, fbe2, stats, out);
}